// Round 11
// baseline (169.727 us; speedup 1.0000x reference)
//
#include <hip/hip_runtime.h>

// Problem constants (match reference)
#define N_PTS 1048576
#define C_PT 9
#define C_LB 20
#define V1 500000
#define V8 65536

// Bucketing: 256 bins per bucket (proven R2 geometry)
#define NB1 1954                 // ceil(V1/256)
#define NB8 256                  // V8/256
#define NBT (NB1 + NB8)          // 2210
#define KBLOCKS 256
#define PTS_PER_BLOCK (N_PTS / KBLOCKS)   // 4096
#define CAP 2048                 // counting-sort chunk (proven R9)

// ---- bf16 helpers (manual RNE; inputs finite; proven R5/R7) ----
__device__ __forceinline__ unsigned f2bf(float f) {
    unsigned u = __float_as_uint(f);
    u += 0x7FFFu + ((u >> 16) & 1u);
    return u >> 16;
}
__device__ __forceinline__ float bf_lo(unsigned w) { return __uint_as_float(w << 16); }
__device__ __forceinline__ float bf_hi(unsigned w) { return __uint_as_float(w & 0xFFFF0000u); }

// K1: per-block LDS histogram over all 2210 buckets -> u16 matrix row.
__global__ __launch_bounds__(1024) void count_kernel(const int* __restrict__ inv1,
                                                     const int* __restrict__ inv8,
                                                     unsigned short* __restrict__ mat)
{
    __shared__ int hist[NBT];
    for (int k = threadIdx.x; k < NBT; k += 1024) hist[k] = 0;
    __syncthreads();
    int base_i = blockIdx.x * PTS_PER_BLOCK;
    for (int t = threadIdx.x; t < PTS_PER_BLOCK; t += 1024) {
        int i = base_i + t;
        atomicAdd(&hist[inv1[i] >> 8], 1);
        atomicAdd(&hist[NB1 + (inv8[i] >> 8)], 1);
    }
    __syncthreads();
    unsigned short* row = mat + (size_t)blockIdx.x * NBT;
    for (int k = threadIdx.x; k < NBT; k += 1024) row[k] = (unsigned short)hist[k];
}

// S1: per-bucket (column) exclusive scan over the 256 blocks, in place.
__global__ __launch_bounds__(256) void colscan_kernel(unsigned short* __restrict__ mat,
                                                      int* __restrict__ total)
{
    int wave = (int)((blockIdx.x * 256 + threadIdx.x) >> 6);
    int lane = threadIdx.x & 63;
    if (wave >= NBT) return;
    int carry = 0;
    for (int c = 0; c < KBLOCKS; c += 64) {
        int b = c + lane;
        int v = (int)mat[(size_t)b * NBT + wave];
        int s = v;
        #pragma unroll
        for (int d = 1; d < 64; d <<= 1) {
            int u = __shfl_up(s, d, 64);
            if (lane >= d) s += u;
        }
        mat[(size_t)b * NBT + wave] = (unsigned short)(s - v + carry);
        carry += __shfl(s, 63, 64);
    }
    if (lane == 0) total[wave] = carry;
}

// S2: exclusive scan of bucket totals -> base (separate per scale).
__global__ __launch_bounds__(64) void basescan_kernel(const int* __restrict__ total,
                                                      int* __restrict__ base)
{
    int lane = threadIdx.x;
    int carry = 0;
    for (int c = 0; c < NB1; c += 64) {
        int k = c + lane;
        int v = (k < NB1) ? total[k] : 0;
        int s = v;
        #pragma unroll
        for (int d = 1; d < 64; d <<= 1) {
            int u = __shfl_up(s, d, 64);
            if (lane >= d) s += u;
        }
        if (k < NB1) base[k] = s - v + carry;
        carry += __shfl(s, 63, 64);
    }
    carry = 0;
    for (int c = 0; c < NB8; c += 64) {
        int k = c + lane;
        int v = total[NB1 + k];
        int s = v;
        #pragma unroll
        for (int d = 1; d < 64; d <<= 1) {
            int u = __shfl_up(s, d, 64);
            if (lane >= d) s += u;
        }
        base[NB1 + k] = s - v + carry;
        carry += __shfl(s, 63, 64);
    }
}

// K2: PAYLOAD scatter (R7 structure, line-aligned rows).
// labels -> lblPay: 64B-stride rows, FULL-LINE uint4 x4 writes (no RMW).
// points -> ptsPay: 32B-stride rows (20B payload; read touches 1 line).
// bins written as separate sequential-readable byte streams.
__global__ __launch_bounds__(1024) void scatter_pay_kernel(const float* __restrict__ points,
                                                           const float* __restrict__ labels,
                                                           const int* __restrict__ inv1,
                                                           const int* __restrict__ inv8,
                                                           const unsigned short* __restrict__ mat,
                                                           const int* __restrict__ base,
                                                           uint4* __restrict__ lblPay,   // [N*4]
                                                           uint4* __restrict__ ptsPay,   // [N*2]
                                                           unsigned char* __restrict__ bins8,  // [N]
                                                           unsigned char* __restrict__ bins1)  // [N]
{
    __shared__ int off[NBT];
    __shared__ int cnt[NBT];
    const unsigned short* row = mat + (size_t)blockIdx.x * NBT;
    for (int k = threadIdx.x; k < NBT; k += 1024) {
        off[k] = base[k] + (int)row[k];
        cnt[k] = 0;
    }
    __syncthreads();
    int base_i = blockIdx.x * PTS_PER_BLOCK;
    for (int t = threadIdx.x; t < PTS_PER_BLOCK; t += 1024) {
        int i = base_i + t;

        int v1 = inv1[i];
        int k1 = v1 >> 8;
        int r1 = atomicAdd(&cnt[k1], 1);
        int dest1 = off[k1] + r1;
        const float* __restrict__ p = points + (size_t)i * C_PT;
        unsigned w0 = f2bf(p[0]) | (f2bf(p[1]) << 16);
        unsigned w1 = f2bf(p[2]) | (f2bf(p[3]) << 16);
        unsigned w2 = f2bf(p[4]) | (f2bf(p[5]) << 16);
        unsigned w3 = f2bf(p[6]) | (f2bf(p[7]) << 16);
        unsigned w4 = f2bf(p[8]);
        uint4* __restrict__ pd = ptsPay + (size_t)dest1 * 2;
        pd[0] = make_uint4(w0, w1, w2, w3);
        pd[1] = make_uint4(w4, 0u, 0u, 0u);
        bins1[dest1] = (unsigned char)(v1 & 255);

        int v8 = inv8[i];
        int k8 = NB1 + (v8 >> 8);
        int r8 = atomicAdd(&cnt[k8], 1);
        int dest8 = off[k8] + r8;
        const float4* __restrict__ l4 = reinterpret_cast<const float4*>(labels) + (size_t)i * 5;
        float4 a0 = l4[0], a1 = l4[1], a2 = l4[2], a3 = l4[3], a4 = l4[4];
        uint4* __restrict__ ld = lblPay + (size_t)dest8 * 4;
        ld[0] = make_uint4(f2bf(a0.x) | (f2bf(a0.y) << 16), f2bf(a0.z) | (f2bf(a0.w) << 16),
                           f2bf(a1.x) | (f2bf(a1.y) << 16), f2bf(a1.z) | (f2bf(a1.w) << 16));
        ld[1] = make_uint4(f2bf(a2.x) | (f2bf(a2.y) << 16), f2bf(a2.z) | (f2bf(a2.w) << 16),
                           f2bf(a3.x) | (f2bf(a3.y) << 16), f2bf(a3.z) | (f2bf(a3.w) << 16));
        ld[2] = make_uint4(f2bf(a4.x) | (f2bf(a4.y) << 16), f2bf(a4.z) | (f2bf(a4.w) << 16), 0u, 0u);
        ld[3] = make_uint4(0u, 0u, 0u, 0u);   // pad -> full 64B line write, no RMW
        bins8[dest8] = (unsigned char)(v8 & 255);
    }
}

// K3: accumulation from bucket-sorted payload (R8/R9 counting-sort structure,
// no per-channel LDS atomics). Histogram reads the sequential bins stream;
// gather fetches EXACTLY one line per row, random only within the chunk's
// 64-128KB window. Thread tid owns voxel bin tid; writes output once.
__global__ __launch_bounds__(256) void accum_sorted_kernel(const uint4* __restrict__ lblPay,
                                                           const uint4* __restrict__ ptsPay,
                                                           const unsigned char* __restrict__ bins8,
                                                           const unsigned char* __restrict__ bins1,
                                                           const int* __restrict__ base,
                                                           const int* __restrict__ total,
                                                           float* __restrict__ feat_out,
                                                           float* __restrict__ lbl_out)
{
    __shared__ unsigned char binbuf[CAP];
    __shared__ unsigned short perm[CAP];
    __shared__ int hist[256];
    __shared__ int starts[256];
    __shared__ int cursor[256];
    __shared__ int wsum[4];

    const int tid  = threadIdx.x;
    const int lane = tid & 63;
    const int wid  = tid >> 6;

    if (blockIdx.x < NB8) {
        // ---------------- labels bucket ----------------
        int b = blockIdx.x;
        int start = base[NB1 + b];
        int num   = total[NB1 + b];
        float acc[C_LB];
        #pragma unroll
        for (int c = 0; c < C_LB; ++c) acc[c] = 0.0f;
        int mycnt = 0;

        for (int cbase = 0; cbase < num; cbase += CAP) {
            int csize = min(CAP, num - cbase);
            __syncthreads();
            for (int t = tid; t < csize; t += 256) binbuf[t] = bins8[start + cbase + t];
            hist[tid] = 0;
            __syncthreads();
            for (int t = tid; t < csize; t += 256) atomicAdd(&hist[(int)binbuf[t]], 1);
            __syncthreads();
            int x = hist[tid];
            int s = x;
            #pragma unroll
            for (int d = 1; d < 64; d <<= 1) {
                int u = __shfl_up(s, d, 64);
                if (lane >= d) s += u;
            }
            if (lane == 63) wsum[wid] = s;
            __syncthreads();
            int off = 0;
            #pragma unroll
            for (int w = 0; w < 4; ++w) if (w < wid) off += wsum[w];
            starts[tid] = off + s - x;
            cursor[tid] = 0;
            __syncthreads();
            for (int t = tid; t < csize; t += 256) {
                int bin = (int)binbuf[t];
                int r = atomicAdd(&cursor[bin], 1);
                perm[starts[bin] + r] = (unsigned short)t;
            }
            __syncthreads();
            int n  = hist[tid];
            int s0 = starts[tid];
            for (int j = 0; j < n; ++j) {
                int r = start + cbase + (int)perm[s0 + j];
                const uint4* __restrict__ ld = lblPay + (size_t)r * 4;
                uint4 x0 = ld[0];
                uint4 x1 = ld[1];
                uint2 x2 = *reinterpret_cast<const uint2*>(ld + 2);
                acc[0]  += bf_lo(x0.x); acc[1]  += bf_hi(x0.x);
                acc[2]  += bf_lo(x0.y); acc[3]  += bf_hi(x0.y);
                acc[4]  += bf_lo(x0.z); acc[5]  += bf_hi(x0.z);
                acc[6]  += bf_lo(x0.w); acc[7]  += bf_hi(x0.w);
                acc[8]  += bf_lo(x1.x); acc[9]  += bf_hi(x1.x);
                acc[10] += bf_lo(x1.y); acc[11] += bf_hi(x1.y);
                acc[12] += bf_lo(x1.z); acc[13] += bf_hi(x1.z);
                acc[14] += bf_lo(x1.w); acc[15] += bf_hi(x1.w);
                acc[16] += bf_lo(x2.x); acc[17] += bf_hi(x2.x);
                acc[18] += bf_lo(x2.y); acc[19] += bf_hi(x2.y);
            }
            mycnt += n;
        }
        float inv = 1.0f / (float)(mycnt > 0 ? mycnt : 1);
        float4* orow = reinterpret_cast<float4*>(lbl_out + ((size_t)b * 256 + tid) * C_LB);
        orow[0] = make_float4(acc[0] * inv,  acc[1] * inv,  acc[2] * inv,  acc[3] * inv);
        orow[1] = make_float4(acc[4] * inv,  acc[5] * inv,  acc[6] * inv,  acc[7] * inv);
        orow[2] = make_float4(acc[8] * inv,  acc[9] * inv,  acc[10] * inv, acc[11] * inv);
        orow[3] = make_float4(acc[12] * inv, acc[13] * inv, acc[14] * inv, acc[15] * inv);
        orow[4] = make_float4(acc[16] * inv, acc[17] * inv, acc[18] * inv, acc[19] * inv);
    } else {
        // ---------------- points bucket ----------------
        int b = blockIdx.x - NB8;
        int start = base[b];
        int num   = total[b];
        float acc[C_PT];
        #pragma unroll
        for (int c = 0; c < C_PT; ++c) acc[c] = 0.0f;
        int mycnt = 0;

        for (int cbase = 0; cbase < num; cbase += CAP) {
            int csize = min(CAP, num - cbase);
            __syncthreads();
            for (int t = tid; t < csize; t += 256) binbuf[t] = bins1[start + cbase + t];
            hist[tid] = 0;
            __syncthreads();
            for (int t = tid; t < csize; t += 256) atomicAdd(&hist[(int)binbuf[t]], 1);
            __syncthreads();
            int x = hist[tid];
            int s = x;
            #pragma unroll
            for (int d = 1; d < 64; d <<= 1) {
                int u = __shfl_up(s, d, 64);
                if (lane >= d) s += u;
            }
            if (lane == 63) wsum[wid] = s;
            __syncthreads();
            int off = 0;
            #pragma unroll
            for (int w = 0; w < 4; ++w) if (w < wid) off += wsum[w];
            starts[tid] = off + s - x;
            cursor[tid] = 0;
            __syncthreads();
            for (int t = tid; t < csize; t += 256) {
                int bin = (int)binbuf[t];
                int r = atomicAdd(&cursor[bin], 1);
                perm[starts[bin] + r] = (unsigned short)t;
            }
            __syncthreads();
            int n  = hist[tid];
            int s0 = starts[tid];
            for (int j = 0; j < n; ++j) {
                int r = start + cbase + (int)perm[s0 + j];
                const uint4* __restrict__ pd = ptsPay + (size_t)r * 2;
                uint4 x0 = pd[0];
                unsigned w4 = *reinterpret_cast<const unsigned*>(pd + 1);
                acc[0] += bf_lo(x0.x); acc[1] += bf_hi(x0.x);
                acc[2] += bf_lo(x0.y); acc[3] += bf_hi(x0.y);
                acc[4] += bf_lo(x0.z); acc[5] += bf_hi(x0.z);
                acc[6] += bf_lo(x0.w); acc[7] += bf_hi(x0.w);
                acc[8] += bf_lo(w4);
            }
            mycnt += n;
        }
        int v = b * 256 + tid;
        if (v < V1) {
            float inv = 1.0f / (float)(mycnt > 0 ? mycnt : 1);
            float* __restrict__ orow = feat_out + (size_t)v * C_PT;
            #pragma unroll
            for (int c = 0; c < C_PT; ++c) orow[c] = acc[c] * inv;
        }
    }
}

// ---------------- Fallback A: R9-proven id-sort + f32 gather ---------------
__global__ __launch_bounds__(1024) void scatter_kernel(const int* __restrict__ inv1,
                                                       const int* __restrict__ inv8,
                                                       const unsigned short* __restrict__ mat,
                                                       const int* __restrict__ base,
                                                       int* __restrict__ sorted1,
                                                       int* __restrict__ sorted8)
{
    __shared__ int off[NBT];
    __shared__ int cnt[NBT];
    const unsigned short* row = mat + (size_t)blockIdx.x * NBT;
    for (int k = threadIdx.x; k < NBT; k += 1024) {
        off[k] = base[k] + (int)row[k];
        cnt[k] = 0;
    }
    __syncthreads();
    int base_i = blockIdx.x * PTS_PER_BLOCK;
    for (int t = threadIdx.x; t < PTS_PER_BLOCK; t += 1024) {
        int i = base_i + t;
        int v1 = inv1[i];
        int k1 = v1 >> 8;
        int r1 = atomicAdd(&cnt[k1], 1);
        sorted1[off[k1] + r1] = i | ((v1 & 255) << 20);
        int v8 = inv8[i];
        int k8 = NB1 + (v8 >> 8);
        int r8 = atomicAdd(&cnt[k8], 1);
        sorted8[off[k8] + r8] = i | ((v8 & 255) << 20);
    }
}

__global__ __launch_bounds__(256) void accum_voxel_kernel(const float* __restrict__ points,
                                                          const float* __restrict__ labels,
                                                          const int* __restrict__ sorted1,
                                                          const int* __restrict__ sorted8,
                                                          const int* __restrict__ base,
                                                          const int* __restrict__ total,
                                                          float* __restrict__ feat_out,
                                                          float* __restrict__ lbl_out)
{
    __shared__ unsigned stage[CAP];
    __shared__ unsigned short perm[CAP];
    __shared__ int hist[256];
    __shared__ int starts[256];
    __shared__ int cursor[256];
    __shared__ int wsum[4];

    const int tid  = threadIdx.x;
    const int lane = tid & 63;
    const int wid  = tid >> 6;

    if (blockIdx.x < NB8) {
        int b = blockIdx.x;
        int start = base[NB1 + b];
        int num   = total[NB1 + b];
        float acc[C_LB];
        #pragma unroll
        for (int c = 0; c < C_LB; ++c) acc[c] = 0.0f;
        int mycnt = 0;
        for (int cbase = 0; cbase < num; cbase += CAP) {
            int csize = min(CAP, num - cbase);
            __syncthreads();
            for (int t = tid; t < csize; t += 256)
                stage[t] = (unsigned)sorted8[start + cbase + t];
            hist[tid] = 0;
            __syncthreads();
            for (int t = tid; t < csize; t += 256) atomicAdd(&hist[stage[t] >> 20], 1);
            __syncthreads();
            int x = hist[tid];
            int s = x;
            #pragma unroll
            for (int d = 1; d < 64; d <<= 1) {
                int u = __shfl_up(s, d, 64);
                if (lane >= d) s += u;
            }
            if (lane == 63) wsum[wid] = s;
            __syncthreads();
            int off = 0;
            #pragma unroll
            for (int w = 0; w < 4; ++w) if (w < wid) off += wsum[w];
            starts[tid] = off + s - x;
            cursor[tid] = 0;
            __syncthreads();
            for (int t = tid; t < csize; t += 256) {
                int bin = (int)(stage[t] >> 20);
                int r = atomicAdd(&cursor[bin], 1);
                perm[starts[bin] + r] = (unsigned short)t;
            }
            __syncthreads();
            int n  = hist[tid];
            int s0 = starts[tid];
            for (int j = 0; j < n; ++j) {
                int t = (int)perm[s0 + j];
                unsigned idx = stage[t] & 0xFFFFFu;
                const float4* __restrict__ r4 =
                    reinterpret_cast<const float4*>(labels) + (size_t)idx * 5;
                float4 v0 = r4[0], v1 = r4[1], v2 = r4[2], v3 = r4[3], v4 = r4[4];
                acc[0]  += v0.x; acc[1]  += v0.y; acc[2]  += v0.z; acc[3]  += v0.w;
                acc[4]  += v1.x; acc[5]  += v1.y; acc[6]  += v1.z; acc[7]  += v1.w;
                acc[8]  += v2.x; acc[9]  += v2.y; acc[10] += v2.z; acc[11] += v2.w;
                acc[12] += v3.x; acc[13] += v3.y; acc[14] += v3.z; acc[15] += v3.w;
                acc[16] += v4.x; acc[17] += v4.y; acc[18] += v4.z; acc[19] += v4.w;
            }
            mycnt += n;
        }
        float inv = 1.0f / (float)(mycnt > 0 ? mycnt : 1);
        float4* orow = reinterpret_cast<float4*>(lbl_out + ((size_t)b * 256 + tid) * C_LB);
        orow[0] = make_float4(acc[0] * inv,  acc[1] * inv,  acc[2] * inv,  acc[3] * inv);
        orow[1] = make_float4(acc[4] * inv,  acc[5] * inv,  acc[6] * inv,  acc[7] * inv);
        orow[2] = make_float4(acc[8] * inv,  acc[9] * inv,  acc[10] * inv, acc[11] * inv);
        orow[3] = make_float4(acc[12] * inv, acc[13] * inv, acc[14] * inv, acc[15] * inv);
        orow[4] = make_float4(acc[16] * inv, acc[17] * inv, acc[18] * inv, acc[19] * inv);
    } else {
        int b = blockIdx.x - NB8;
        int start = base[b];
        int num   = total[b];
        float acc[C_PT];
        #pragma unroll
        for (int c = 0; c < C_PT; ++c) acc[c] = 0.0f;
        int mycnt = 0;
        for (int cbase = 0; cbase < num; cbase += CAP) {
            int csize = min(CAP, num - cbase);
            __syncthreads();
            for (int t = tid; t < csize; t += 256)
                stage[t] = (unsigned)sorted1[start + cbase + t];
            hist[tid] = 0;
            __syncthreads();
            for (int t = tid; t < csize; t += 256) atomicAdd(&hist[stage[t] >> 20], 1);
            __syncthreads();
            int x = hist[tid];
            int s = x;
            #pragma unroll
            for (int d = 1; d < 64; d <<= 1) {
                int u = __shfl_up(s, d, 64);
                if (lane >= d) s += u;
            }
            if (lane == 63) wsum[wid] = s;
            __syncthreads();
            int off = 0;
            #pragma unroll
            for (int w = 0; w < 4; ++w) if (w < wid) off += wsum[w];
            starts[tid] = off + s - x;
            cursor[tid] = 0;
            __syncthreads();
            for (int t = tid; t < csize; t += 256) {
                int bin = (int)(stage[t] >> 20);
                int r = atomicAdd(&cursor[bin], 1);
                perm[starts[bin] + r] = (unsigned short)t;
            }
            __syncthreads();
            int n  = hist[tid];
            int s0 = starts[tid];
            for (int j = 0; j < n; ++j) {
                int t = (int)perm[s0 + j];
                unsigned idx = stage[t] & 0xFFFFFu;
                const float* __restrict__ r = points + (size_t)idx * C_PT;
                float p0 = r[0], p1 = r[1], p2 = r[2], p3 = r[3], p4 = r[4];
                float p5 = r[5], p6 = r[6], p7 = r[7], p8 = r[8];
                acc[0] += p0; acc[1] += p1; acc[2] += p2; acc[3] += p3;
                acc[4] += p4; acc[5] += p5; acc[6] += p6; acc[7] += p7;
                acc[8] += p8;
            }
            mycnt += n;
        }
        int v = b * 256 + tid;
        if (v < V1) {
            float inv = 1.0f / (float)(mycnt > 0 ? mycnt : 1);
            float* __restrict__ orow = feat_out + (size_t)v * C_PT;
            #pragma unroll
            for (int c = 0; c < C_PT; ++c) orow[c] = acc[c] * inv;
        }
    }
}

// ---------------- Fallback B: R0 atomic scatter ----------------------------
__global__ void voxel_scatter_add_kernel(const float* __restrict__ points,
                                         const int* __restrict__ inv1,
                                         const float* __restrict__ labels,
                                         const int* __restrict__ inv8,
                                         float* feat_sum, float* lbl_sum,
                                         float* cnt1, float* cnt8)
{
    int i = blockIdx.x * blockDim.x + threadIdx.x;
    if (i >= N_PTS) return;
    int v1 = inv1[i];
    int v8 = inv8[i];
    const float* p = points + (size_t)i * C_PT;
    float* f = feat_sum + (size_t)v1 * C_PT;
#pragma unroll
    for (int c = 0; c < C_PT; ++c) atomicAdd(&f[c], p[c]);
    atomicAdd(&cnt1[v1], 1.0f);
    const float* l = labels + (size_t)i * C_LB;
    float* o = lbl_sum + (size_t)v8 * C_LB;
#pragma unroll
    for (int c = 0; c < C_LB; ++c) atomicAdd(&o[c], l[c]);
    atomicAdd(&cnt8[v8], 1.0f);
}

__global__ void voxel_divide_kernel(float* out, const float* cnt1, const float* cnt8)
{
    const int totaln = V1 * C_PT + V8 * C_LB;
    for (int i = blockIdx.x * blockDim.x + threadIdx.x; i < totaln;
         i += gridDim.x * blockDim.x) {
        float c = (i < V1 * C_PT) ? cnt1[i / C_PT] : cnt8[(i - V1 * C_PT) / C_LB];
        out[i] /= fmaxf(c, 1.0f);
    }
}

extern "C" void kernel_launch(void* const* d_in, const int* in_sizes, int n_in,
                              void* d_out, int out_size, void* d_ws, size_t ws_size,
                              hipStream_t stream) {
    const float* points = (const float*)d_in[0];
    const int*   inv1   = (const int*)d_in[1];
    const float* labels = (const float*)d_in[2];
    const int*   inv8   = (const int*)d_in[3];

    float* out      = (float*)d_out;
    float* feat_out = out;                       // [V1, C_PT]
    float* lbl_out  = out + (size_t)V1 * C_PT;   // [V8, C_LB]

    // Primary layout: lblPay uint4[N*4] (64MB) | ptsPay uint4[N*2] (32MB) |
    //                 bins8 u8[N] | bins1 u8[N] | total | base | mat  (~99.3MB)
    const size_t pay_need = (size_t)N_PTS * 96 + (size_t)N_PTS * 2
                          + (size_t)2 * NBT * sizeof(int)
                          + (size_t)KBLOCKS * NBT * sizeof(unsigned short);
    // Fallback A (R9 exact): ~9.45MB
    const size_t idx_need = ((size_t)2 * N_PTS + 2 * NBT) * sizeof(int)
                          + (size_t)KBLOCKS * NBT * sizeof(unsigned short);
    const int block = 256;

    if (ws_size >= pay_need) {
        uint4* lblPay = (uint4*)d_ws;
        uint4* ptsPay = lblPay + (size_t)N_PTS * 4;
        unsigned char* bins8 = (unsigned char*)(ptsPay + (size_t)N_PTS * 2);
        unsigned char* bins1 = bins8 + N_PTS;
        int* total = (int*)(bins1 + N_PTS);
        int* basep = total + NBT;
        unsigned short* mat = (unsigned short*)(basep + NBT);

        count_kernel<<<KBLOCKS, 1024, 0, stream>>>(inv1, inv8, mat);
        colscan_kernel<<<(NBT + 3) / 4, 256, 0, stream>>>(mat, total);
        basescan_kernel<<<1, 64, 0, stream>>>(total, basep);
        scatter_pay_kernel<<<KBLOCKS, 1024, 0, stream>>>(points, labels, inv1, inv8,
                                                         mat, basep, lblPay, ptsPay,
                                                         bins8, bins1);
        accum_sorted_kernel<<<NB8 + NB1, 256, 0, stream>>>(lblPay, ptsPay, bins8, bins1,
                                                           basep, total,
                                                           feat_out, lbl_out);
    } else if (ws_size >= idx_need) {
        // Fallback A: R9-proven path (109.5us).
        int* sorted1 = (int*)d_ws;
        int* sorted8 = sorted1 + N_PTS;
        int* total   = sorted8 + N_PTS;
        int* basep   = total + NBT;
        unsigned short* mat = (unsigned short*)(basep + NBT);

        count_kernel<<<KBLOCKS, 1024, 0, stream>>>(inv1, inv8, mat);
        colscan_kernel<<<(NBT + 3) / 4, 256, 0, stream>>>(mat, total);
        basescan_kernel<<<1, 64, 0, stream>>>(total, basep);
        scatter_kernel<<<KBLOCKS, 1024, 0, stream>>>(inv1, inv8, mat, basep,
                                                     sorted1, sorted8);
        accum_voxel_kernel<<<NB8 + NB1, 256, 0, stream>>>(points, labels, sorted1,
                                                          sorted8, basep, total,
                                                          feat_out, lbl_out);
    } else {
        float* cnt1 = (float*)d_ws;
        float* cnt8 = cnt1 + V1;
        hipMemsetAsync(d_out, 0, (size_t)out_size * sizeof(float), stream);
        hipMemsetAsync(d_ws, 0, ((size_t)V1 + V8) * sizeof(float), stream);
        voxel_scatter_add_kernel<<<(N_PTS + block - 1) / block, block, 0, stream>>>(
            points, inv1, labels, inv8, feat_out, lbl_out, cnt1, cnt8);
        voxel_divide_kernel<<<2048, block, 0, stream>>>(out, cnt1, cnt8);
    }
}

// Round 12
// 109.323 us; speedup vs baseline: 1.5525x; 1.5525x over previous
//
#include <hip/hip_runtime.h>

// Problem constants (match reference)
#define N_PTS 1048576
#define C_PT 9
#define C_LB 20
#define V1 500000
#define V8 65536

// Bucketing: 256 bins per bucket (proven R2 geometry)
#define NB1 1954                 // ceil(V1/256)
#define NB8 256                  // V8/256
#define NBT (NB1 + NB8)          // 2210
#define KBLOCKS 256
#define PTS_PER_BLOCK (N_PTS / KBLOCKS)   // 4096
#define CAP 2048                 // counting-sort chunk (proven R9: ~15KB LDS)

// K1: per-block LDS histogram over all 2210 buckets -> u16 matrix row.
__global__ __launch_bounds__(1024) void count_kernel(const int* __restrict__ inv1,
                                                     const int* __restrict__ inv8,
                                                     unsigned short* __restrict__ mat)
{
    __shared__ int hist[NBT];
    for (int k = threadIdx.x; k < NBT; k += 1024) hist[k] = 0;
    __syncthreads();
    int base_i = blockIdx.x * PTS_PER_BLOCK;
    for (int t = threadIdx.x; t < PTS_PER_BLOCK; t += 1024) {
        int i = base_i + t;
        atomicAdd(&hist[inv1[i] >> 8], 1);
        atomicAdd(&hist[NB1 + (inv8[i] >> 8)], 1);
    }
    __syncthreads();
    unsigned short* row = mat + (size_t)blockIdx.x * NBT;
    for (int k = threadIdx.x; k < NBT; k += 1024) row[k] = (unsigned short)hist[k];
}

// S1: per-bucket (column) exclusive scan over the 256 blocks, in place.
__global__ __launch_bounds__(256) void colscan_kernel(unsigned short* __restrict__ mat,
                                                      int* __restrict__ total)
{
    int wave = (int)((blockIdx.x * 256 + threadIdx.x) >> 6);
    int lane = threadIdx.x & 63;
    if (wave >= NBT) return;
    int carry = 0;
    for (int c = 0; c < KBLOCKS; c += 64) {
        int b = c + lane;
        int v = (int)mat[(size_t)b * NBT + wave];
        int s = v;
        #pragma unroll
        for (int d = 1; d < 64; d <<= 1) {
            int u = __shfl_up(s, d, 64);
            if (lane >= d) s += u;
        }
        mat[(size_t)b * NBT + wave] = (unsigned short)(s - v + carry);
        carry += __shfl(s, 63, 64);
    }
    if (lane == 0) total[wave] = carry;
}

// S2: exclusive scan of bucket totals -> base (separate per scale).
__global__ __launch_bounds__(64) void basescan_kernel(const int* __restrict__ total,
                                                      int* __restrict__ base)
{
    int lane = threadIdx.x;
    int carry = 0;
    for (int c = 0; c < NB1; c += 64) {
        int k = c + lane;
        int v = (k < NB1) ? total[k] : 0;
        int s = v;
        #pragma unroll
        for (int d = 1; d < 64; d <<= 1) {
            int u = __shfl_up(s, d, 64);
            if (lane >= d) s += u;
        }
        if (k < NB1) base[k] = s - v + carry;
        carry += __shfl(s, 63, 64);
    }
    carry = 0;
    for (int c = 0; c < NB8; c += 64) {
        int k = c + lane;
        int v = total[NB1 + k];
        int s = v;
        #pragma unroll
        for (int d = 1; d < 64; d <<= 1) {
            int u = __shfl_up(s, d, 64);
            if (lane >= d) s += u;
        }
        base[NB1 + k] = s - v + carry;
        carry += __shfl(s, 63, 64);
    }
}

// K2: place each point id (packed with 8-bit in-bucket bin) into sorted arrays.
__global__ __launch_bounds__(1024) void scatter_kernel(const int* __restrict__ inv1,
                                                       const int* __restrict__ inv8,
                                                       const unsigned short* __restrict__ mat,
                                                       const int* __restrict__ base,
                                                       int* __restrict__ sorted1,
                                                       int* __restrict__ sorted8)
{
    __shared__ int off[NBT];
    __shared__ int cnt[NBT];
    const unsigned short* row = mat + (size_t)blockIdx.x * NBT;
    for (int k = threadIdx.x; k < NBT; k += 1024) {
        off[k] = base[k] + (int)row[k];
        cnt[k] = 0;
    }
    __syncthreads();
    int base_i = blockIdx.x * PTS_PER_BLOCK;
    for (int t = threadIdx.x; t < PTS_PER_BLOCK; t += 1024) {
        int i = base_i + t;
        int v1 = inv1[i];
        int k1 = v1 >> 8;
        int r1 = atomicAdd(&cnt[k1], 1);
        sorted1[off[k1] + r1] = i | ((v1 & 255) << 20);
        int v8 = inv8[i];
        int k8 = NB1 + (v8 >> 8);
        int r8 = atomicAdd(&cnt[k8], 1);
        sorted8[off[k8] + r8] = i | ((v8 & 255) << 20);
    }
}

// K3: accumulation without per-channel LDS atomics (R8 structure, R9 tuning).
// Per bucket: in-LDS counting sort of row indices by bin (2 LDS atomics/row),
// then thread v register-accumulates its voxel's contiguous row list with
// plain f32 gathers (no atomics, latency-bound random line fetch), divides,
// writes output exactly once. Measured at ~38.5 G random lines/s — the fabric
// ceiling independently confirmed by R1's linked-list walk (~37 G lines/s).
__global__ __launch_bounds__(256) void accum_voxel_kernel(const float* __restrict__ points,
                                                          const float* __restrict__ labels,
                                                          const int* __restrict__ sorted1,
                                                          const int* __restrict__ sorted8,
                                                          const int* __restrict__ base,
                                                          const int* __restrict__ total,
                                                          float* __restrict__ feat_out,
                                                          float* __restrict__ lbl_out)
{
    __shared__ unsigned stage[CAP];        // sorted words of current chunk (8KB)
    __shared__ unsigned short perm[CAP];   // bin-sorted row order (4KB)
    __shared__ int hist[256];
    __shared__ int starts[256];
    __shared__ int cursor[256];
    __shared__ int wsum[4];

    const int tid  = threadIdx.x;
    const int lane = tid & 63;
    const int wid  = tid >> 6;

    if (blockIdx.x < NB8) {
        // ---------------- labels bucket ----------------
        int b = blockIdx.x;
        int start = base[NB1 + b];
        int num   = total[NB1 + b];
        float acc[C_LB];
        #pragma unroll
        for (int c = 0; c < C_LB; ++c) acc[c] = 0.0f;
        int mycnt = 0;

        for (int cbase = 0; cbase < num; cbase += CAP) {
            int csize = min(CAP, num - cbase);
            __syncthreads();                       // protect stage/perm reuse
            for (int t = tid; t < csize; t += 256)
                stage[t] = (unsigned)sorted8[start + cbase + t];
            hist[tid] = 0;
            __syncthreads();
            for (int t = tid; t < csize; t += 256)
                atomicAdd(&hist[stage[t] >> 20], 1);
            __syncthreads();
            // exclusive scan of hist (4-wave shfl scan + cross-wave offsets)
            int x = hist[tid];
            int s = x;
            #pragma unroll
            for (int d = 1; d < 64; d <<= 1) {
                int u = __shfl_up(s, d, 64);
                if (lane >= d) s += u;
            }
            if (lane == 63) wsum[wid] = s;
            __syncthreads();
            int off = 0;
            #pragma unroll
            for (int w = 0; w < 4; ++w) if (w < wid) off += wsum[w];
            starts[tid] = off + s - x;
            cursor[tid] = 0;
            __syncthreads();
            // rank: place row index into per-bin contiguous region
            for (int t = tid; t < csize; t += 256) {
                int bin = (int)(stage[t] >> 20);
                int r = atomicAdd(&cursor[bin], 1);
                perm[starts[bin] + r] = (unsigned short)t;
            }
            __syncthreads();
            // gather: thread tid owns voxel (b*256 + tid)
            int n  = hist[tid];
            int s0 = starts[tid];
            for (int j = 0; j < n; ++j) {
                int t = (int)perm[s0 + j];
                unsigned idx = stage[t] & 0xFFFFFu;
                const float4* __restrict__ r4 =
                    reinterpret_cast<const float4*>(labels) + (size_t)idx * 5;
                float4 v0 = r4[0], v1 = r4[1], v2 = r4[2], v3 = r4[3], v4 = r4[4];
                acc[0]  += v0.x; acc[1]  += v0.y; acc[2]  += v0.z; acc[3]  += v0.w;
                acc[4]  += v1.x; acc[5]  += v1.y; acc[6]  += v1.z; acc[7]  += v1.w;
                acc[8]  += v2.x; acc[9]  += v2.y; acc[10] += v2.z; acc[11] += v2.w;
                acc[12] += v3.x; acc[13] += v3.y; acc[14] += v3.z; acc[15] += v3.w;
                acc[16] += v4.x; acc[17] += v4.y; acc[18] += v4.z; acc[19] += v4.w;
            }
            mycnt += n;
        }
        float inv = 1.0f / (float)(mycnt > 0 ? mycnt : 1);
        // lbl_out base offset = V1*C_PT floats (16B-aligned); 80B rows.
        float4* orow = reinterpret_cast<float4*>(lbl_out + ((size_t)b * 256 + tid) * C_LB);
        orow[0] = make_float4(acc[0] * inv,  acc[1] * inv,  acc[2] * inv,  acc[3] * inv);
        orow[1] = make_float4(acc[4] * inv,  acc[5] * inv,  acc[6] * inv,  acc[7] * inv);
        orow[2] = make_float4(acc[8] * inv,  acc[9] * inv,  acc[10] * inv, acc[11] * inv);
        orow[3] = make_float4(acc[12] * inv, acc[13] * inv, acc[14] * inv, acc[15] * inv);
        orow[4] = make_float4(acc[16] * inv, acc[17] * inv, acc[18] * inv, acc[19] * inv);
    } else {
        // ---------------- points bucket ----------------
        int b = blockIdx.x - NB8;
        int start = base[b];
        int num   = total[b];
        float acc[C_PT];
        #pragma unroll
        for (int c = 0; c < C_PT; ++c) acc[c] = 0.0f;
        int mycnt = 0;

        for (int cbase = 0; cbase < num; cbase += CAP) {
            int csize = min(CAP, num - cbase);
            __syncthreads();
            for (int t = tid; t < csize; t += 256)
                stage[t] = (unsigned)sorted1[start + cbase + t];
            hist[tid] = 0;
            __syncthreads();
            for (int t = tid; t < csize; t += 256)
                atomicAdd(&hist[stage[t] >> 20], 1);
            __syncthreads();
            int x = hist[tid];
            int s = x;
            #pragma unroll
            for (int d = 1; d < 64; d <<= 1) {
                int u = __shfl_up(s, d, 64);
                if (lane >= d) s += u;
            }
            if (lane == 63) wsum[wid] = s;
            __syncthreads();
            int off = 0;
            #pragma unroll
            for (int w = 0; w < 4; ++w) if (w < wid) off += wsum[w];
            starts[tid] = off + s - x;
            cursor[tid] = 0;
            __syncthreads();
            for (int t = tid; t < csize; t += 256) {
                int bin = (int)(stage[t] >> 20);
                int r = atomicAdd(&cursor[bin], 1);
                perm[starts[bin] + r] = (unsigned short)t;
            }
            __syncthreads();
            int n  = hist[tid];
            int s0 = starts[tid];
            for (int j = 0; j < n; ++j) {
                int t = (int)perm[s0 + j];
                unsigned idx = stage[t] & 0xFFFFFu;
                const float* __restrict__ r = points + (size_t)idx * C_PT;
                float p0 = r[0], p1 = r[1], p2 = r[2], p3 = r[3], p4 = r[4];
                float p5 = r[5], p6 = r[6], p7 = r[7], p8 = r[8];
                acc[0] += p0; acc[1] += p1; acc[2] += p2; acc[3] += p3;
                acc[4] += p4; acc[5] += p5; acc[6] += p6; acc[7] += p7;
                acc[8] += p8;
            }
            mycnt += n;
        }
        int v = b * 256 + tid;
        if (v < V1) {
            float inv = 1.0f / (float)(mycnt > 0 ? mycnt : 1);
            float* __restrict__ orow = feat_out + (size_t)v * C_PT;
            #pragma unroll
            for (int c = 0; c < C_PT; ++c) orow[c] = acc[c] * inv;
        }
    }
}

// ---------------- Fallback: R0 atomic scatter (ws tiny) --------------------
__global__ void voxel_scatter_add_kernel(const float* __restrict__ points,
                                         const int* __restrict__ inv1,
                                         const float* __restrict__ labels,
                                         const int* __restrict__ inv8,
                                         float* feat_sum, float* lbl_sum,
                                         float* cnt1, float* cnt8)
{
    int i = blockIdx.x * blockDim.x + threadIdx.x;
    if (i >= N_PTS) return;
    int v1 = inv1[i];
    int v8 = inv8[i];
    const float* p = points + (size_t)i * C_PT;
    float* f = feat_sum + (size_t)v1 * C_PT;
#pragma unroll
    for (int c = 0; c < C_PT; ++c) atomicAdd(&f[c], p[c]);
    atomicAdd(&cnt1[v1], 1.0f);
    const float* l = labels + (size_t)i * C_LB;
    float* o = lbl_sum + (size_t)v8 * C_LB;
#pragma unroll
    for (int c = 0; c < C_LB; ++c) atomicAdd(&o[c], l[c]);
    atomicAdd(&cnt8[v8], 1.0f);
}

__global__ void voxel_divide_kernel(float* out, const float* cnt1, const float* cnt8)
{
    const int totaln = V1 * C_PT + V8 * C_LB;
    for (int i = blockIdx.x * blockDim.x + threadIdx.x; i < totaln;
         i += gridDim.x * blockDim.x) {
        float c = (i < V1 * C_PT) ? cnt1[i / C_PT] : cnt8[(i - V1 * C_PT) / C_LB];
        out[i] /= fmaxf(c, 1.0f);
    }
}

extern "C" void kernel_launch(void* const* d_in, const int* in_sizes, int n_in,
                              void* d_out, int out_size, void* d_ws, size_t ws_size,
                              hipStream_t stream) {
    const float* points = (const float*)d_in[0];
    const int*   inv1   = (const int*)d_in[1];
    const float* labels = (const float*)d_in[2];
    const int*   inv8   = (const int*)d_in[3];

    float* out      = (float*)d_out;
    float* feat_out = out;                       // [V1, C_PT]
    float* lbl_out  = out + (size_t)V1 * C_PT;   // [V8, C_LB]

    // ws layout (EXACT R9, proven): sorted1[N] | sorted8[N] | total[NBT] |
    //                               base[NBT] | mat u16[256][NBT]   (~9.45 MB)
    const size_t need = ((size_t)2 * N_PTS + 2 * NBT) * sizeof(int)
                      + (size_t)KBLOCKS * NBT * sizeof(unsigned short);
    if (ws_size >= need) {
        int* sorted1 = (int*)d_ws;
        int* sorted8 = sorted1 + N_PTS;
        int* total   = sorted8 + N_PTS;
        int* basep   = total + NBT;
        unsigned short* mat = (unsigned short*)(basep + NBT);

        count_kernel<<<KBLOCKS, 1024, 0, stream>>>(inv1, inv8, mat);
        colscan_kernel<<<(NBT + 3) / 4, 256, 0, stream>>>(mat, total);
        basescan_kernel<<<1, 64, 0, stream>>>(total, basep);
        scatter_kernel<<<KBLOCKS, 1024, 0, stream>>>(inv1, inv8, mat, basep,
                                                     sorted1, sorted8);
        accum_voxel_kernel<<<NB8 + NB1, 256, 0, stream>>>(points, labels, sorted1,
                                                          sorted8, basep, total,
                                                          feat_out, lbl_out);
    } else {
        // Fallback: naive atomic scatter (correct, slower).
        float* cnt1 = (float*)d_ws;
        float* cnt8 = cnt1 + V1;
        hipMemsetAsync(d_out, 0, (size_t)out_size * sizeof(float), stream);
        hipMemsetAsync(d_ws, 0, ((size_t)V1 + V8) * sizeof(float), stream);
        const int block = 256;
        voxel_scatter_add_kernel<<<(N_PTS + block - 1) / block, block, 0, stream>>>(
            points, inv1, labels, inv8, feat_out, lbl_out, cnt1, cnt8);
        voxel_divide_kernel<<<2048, block, 0, stream>>>(out, cnt1, cnt8);
    }
}